// Round 3
// baseline (593.209 us; speedup 1.0000x reference)
//
#include <hip/hip_runtime.h>
#include <math.h>

#define NB 32768
#define NT 48
#define NH 32
#define NOH 16
#define NK 3
#define NS 6
#define NSUB 4

typedef float f2 __attribute__((ext_vector_type(2)));

__device__ __forceinline__ f2 fma2(f2 a, f2 b, f2 c) {
    return __builtin_elementwise_fma(a, b, c);
}
__device__ __forceinline__ f2 bc2(float x) { f2 r; r.x = x; r.y = x; return r; }

// butterfly all-reduce over the 8-lane element group {r, r^1, r^2, r^8 ...}
// all three stages are DPP (VALU pipe): xor1/xor2 = quad_perm, xor8 = row_ror:8
template<int CTRL>
__device__ __forceinline__ float dpp_add(float v) {
    int x = __builtin_amdgcn_update_dpp(0, __float_as_int(v), CTRL, 0xF, 0xF, false);
    return v + __int_as_float(x);
}
__device__ __forceinline__ float qsum8(float v) {
    v = dpp_add<0xB1>(v);   // quad_perm [1,0,3,2]  : xor1
    v = dpp_add<0x4E>(v);   // quad_perm [2,3,0,1]  : xor2
    v = dpp_add<0x128>(v);  // row_ror:8            : xor8 (within 16-lane row)
    return v;
}

__device__ __forceinline__ float fast_tanh_scalar(float x) {
    float e = __builtin_amdgcn_exp2f(2.88539008177792681472f * x);
    return 1.0f - 2.0f * __builtin_amdgcn_rcpf(e + 1.0f);
}
__device__ __forceinline__ float gelu_exact(float x) {
    return 0.5f * x * (1.0f + erff(x * 0.70710678118654752440f));
}

__global__ void __launch_bounds__(256, 4) pinod_kernel(
    const float* __restrict__ expr,
    const float* __restrict__ t_eval,
    const float* __restrict__ enc_w1,
    const float* __restrict__ enc_b1,
    const float* __restrict__ ln_g,
    const float* __restrict__ ln_b,
    const float* __restrict__ enc_w2,
    const float* __restrict__ enc_b2,
    const float* __restrict__ enc_w3,
    const float* __restrict__ enc_b3,
    const float* __restrict__ periods,
    const float* __restrict__ gammav,
    const float* __restrict__ ode_w1,
    const float* __restrict__ ode_b1,
    const float* __restrict__ ode_w2,
    const float* __restrict__ ode_b2,
    const float* __restrict__ dec_w,
    const float* __restrict__ dec_b,
    const float* __restrict__ baseline,
    float* __restrict__ out)
{
    const int tid  = blockIdx.x * 256 + threadIdx.x;
    const int lane = threadIdx.x & 63;
    // element group = lanes {base, +1, +2, +3, +8, +9, +10, +11}; closed under xor1/2/8
    const int sub  = (lane & 3) | ((lane & 8) >> 1);              // 0..7 within group
    const int b    = (tid >> 6) * 8 + ((lane >> 4) * 2) + ((lane >> 2) & 1);

    float* out_eh  = out;                                          // [NB][NT]
    float* out_tr  = out + (size_t)NB * NT;                        // [NT][NB][NS]
    float* out_amp = out + (size_t)NB * NT + (size_t)NT * NB * NS; // [NB][NK]

    // ================= encoder (8-way split: 4 h-units per lane) =============
    const int base4 = sub * 4;
    float h1r[4];
    {
        float4 b0 = *(const float4*)(enc_b1 + base4);
        h1r[0] = b0.x; h1r[1] = b0.y; h1r[2] = b0.z; h1r[3] = b0.w;
    }
    const float4* xp = (const float4*)(expr + (size_t)b * NT);
    #pragma unroll 1
    for (int t4 = 0; t4 < NT / 4; ++t4) {
        float4 xq = xp[t4];
        float xs[4] = {xq.x, xq.y, xq.z, xq.w};
        #pragma unroll
        for (int u4 = 0; u4 < 4; ++u4) {
            int t = t4 * 4 + u4;
            float4 w = *(const float4*)(enc_w1 + t * NH + base4);
            float x = xs[u4];
            h1r[0] = fmaf(x, w.x, h1r[0]); h1r[1] = fmaf(x, w.y, h1r[1]);
            h1r[2] = fmaf(x, w.z, h1r[2]); h1r[3] = fmaf(x, w.w, h1r[3]);
        }
    }
    // layernorm across all 32 (cross-lane) + gelu
    {
        float s = h1r[0] + h1r[1] + h1r[2] + h1r[3];
        float mu = qsum8(s) * (1.0f / NH);
        float v = 0.f;
        #pragma unroll
        for (int u = 0; u < 4; ++u) { float d = h1r[u] - mu; v = fmaf(d, d, v); }
        float var = qsum8(v) * (1.0f / NH);
        float rstd = rsqrtf(var + 1e-5f);
        float4 g = *(const float4*)(ln_g + base4);
        float4 l = *(const float4*)(ln_b + base4);
        float gg[4] = {g.x, g.y, g.z, g.w};
        float ll[4] = {l.x, l.y, l.z, l.w};
        #pragma unroll
        for (int u = 0; u < 4; ++u)
            h1r[u] = gelu_exact((h1r[u] - mu) * rstd * gg[u] + ll[u]);
    }
    // h2 = gelu(h1 @ w2 + b2): lane owns j2 in [base4, base4+4)
    float acc[4];
    {
        float4 b0 = *(const float4*)(enc_b2 + base4);
        acc[0] = b0.x; acc[1] = b0.y; acc[2] = b0.z; acc[3] = b0.w;
    }
    const int gbase = lane & 0x34;  // clear bits 0,1,3 -> group base lane
    #pragma unroll 1
    for (int g = 0; g < 8; ++g) {
        int src = gbase + (g & 3) + ((g & 4) << 1);
        #pragma unroll
        for (int u = 0; u < 4; ++u) {
            float hv = __shfl(h1r[u], src, 64);
            int j = g * 4 + u;
            float4 w = *(const float4*)(enc_w2 + j * NH + base4);
            acc[0] = fmaf(hv, w.x, acc[0]); acc[1] = fmaf(hv, w.y, acc[1]);
            acc[2] = fmaf(hv, w.z, acc[2]); acc[3] = fmaf(hv, w.w, acc[3]);
        }
    }
    // z0 = gelu(acc) @ w3 + b3, butterfly-reduced -> replicated in all 8 lanes
    f2 z[3];
    {
        float zp[NS] = {0.f, 0.f, 0.f, 0.f, 0.f, 0.f};
        #pragma unroll
        for (int q = 0; q < 4; ++q) {
            float gm = gelu_exact(acc[q]);
            const float2* wp = (const float2*)(enc_w3 + (base4 + q) * NS);
            float2 w0 = wp[0], w1 = wp[1], w2 = wp[2];
            zp[0] = fmaf(gm, w0.x, zp[0]); zp[1] = fmaf(gm, w0.y, zp[1]);
            zp[2] = fmaf(gm, w1.x, zp[2]); zp[3] = fmaf(gm, w1.y, zp[3]);
            zp[4] = fmaf(gm, w2.x, zp[4]); zp[5] = fmaf(gm, w2.y, zp[5]);
        }
        #pragma unroll
        for (int s = 0; s < 3; ++s) {
            z[s].x = qsum8(zp[2 * s])     + enc_b3[2 * s];
            z[s].y = qsum8(zp[2 * s + 1]) + enc_b3[2 * s + 1];
        }
    }

    // ======== ODE weights: lane owns 2 hidden units (VGPR-resident) ==========
    const int obase = sub * 2;
    f2 w1c[NS];                        // w1c[i] = ode_w1[i][obase..obase+2)
    #pragma unroll
    for (int i = 0; i < NS; ++i) {
        float2 w = *(const float2*)(ode_w1 + i * NOH + obase);
        w1c[i].x = w.x; w1c[i].y = w.y;
    }
    f2 b1r2;
    {
        float2 w = *(const float2*)(ode_b1 + obase);
        b1r2.x = w.x; b1r2.y = w.y;
    }
    f2 w2r2[2][3];                     // [unit][state-pair]
    #pragma unroll
    for (int u = 0; u < 2; ++u) {
        const float2* wp = (const float2*)(ode_w2 + (obase + u) * NS);
        #pragma unroll
        for (int s = 0; s < 3; ++s) {
            float2 w = wp[s];
            w2r2[u][s].x = w.x; w2r2[u][s].y = w.y;
        }
    }

    float om2[NK], tg[NK], dw[NK];
    #pragma unroll
    for (int k = 0; k < NK; ++k) {
        float w = 6.28318530717958647693f / periods[k];
        om2[k] = w * w;
        tg[k]  = 2.0f * gammav[k];
        dw[k]  = dec_w[k];
    }
    f2 b2r[3];
    #pragma unroll
    for (int s = 0; s < 3; ++s) {
        float2 w = *(const float2*)(ode_b2 + 2 * s);
        b2r[s].x = w.x; b2r[s].y = w.y;
    }
    const float addc = dec_b[0] + baseline[0];

    auto deriv = [&](const f2 (&zz)[3], f2 (&d)[3]) {
        // a = z @ w1 + b1 for this lane's 2 hidden units (packed)
        f2 a = b1r2;
        #pragma unroll
        for (int i = 0; i < 3; ++i) {
            a = fma2(bc2(zz[i].x), w1c[2 * i],     a);
            a = fma2(bc2(zz[i].y), w1c[2 * i + 1], a);
        }
        // tanh(a) both halves: 1 - 2/(exp(2a)+1)
        f2 t = a * bc2(2.88539008177792681472f);
        f2 e; e.x = __builtin_amdgcn_exp2f(t.x); e.y = __builtin_amdgcn_exp2f(t.y);
        f2 r = e + bc2(1.0f);
        f2 rc; rc.x = __builtin_amdgcn_rcpf(r.x); rc.y = __builtin_amdgcn_rcpf(r.y);
        f2 y = fma2(bc2(-2.0f), rc, bc2(1.0f));
        // partial correction, butterfly-reduce, assemble base dynamics
        #pragma unroll
        for (int s = 0; s < 3; ++s) {
            f2 p = fma2(bc2(y.y), w2r2[1][s], bc2(y.x) * w2r2[0][s]);
            p.x = qsum8(p.x); p.y = qsum8(p.y);
            float xx = zz[s].x, vv = zz[s].y;
            f2 lin; lin.x = vv; lin.y = fmaf(-om2[s], xx, -tg[s] * vv);
            d[s] = lin + p + b2r[s];
        }
    };

    // ================= t = 0 outputs =================
    float amp[NK];
    {
        float eh = addc;
        #pragma unroll
        for (int k = 0; k < NK; ++k) {
            float xx = z[k].x;
            amp[k] = xx * xx;
            eh = fmaf(xx, dw[k], eh);
        }
        if (sub == 0) out_eh[(size_t)b * NT] = eh;
        if (sub < 3) {
            float2 st = {z[sub].x, z[sub].y};
            *(float2*)(out_tr + (size_t)b * NS + 2 * sub) = st;
        }
    }

    // ================= integrate =================
    #pragma unroll 1
    for (int t = 1; t < NT; ++t) {
        const float dt  = t_eval[t] - t_eval[t - 1];
        const float hh  = dt * (1.0f / NSUB);
        const float hh2 = 0.5f * hh;
        const float hh6 = hh * (1.0f / 6.0f);
        #pragma unroll 1
        for (int ss = 0; ss < NSUB; ++ss) {
            f2 d[3], zt[3], zs[3];
            deriv(z, d);                                        // k1
            #pragma unroll
            for (int s = 0; s < 3; ++s) { zs[s] = d[s]; zt[s] = fma2(bc2(hh2), d[s], z[s]); }
            deriv(zt, d);                                       // k2
            #pragma unroll
            for (int s = 0; s < 3; ++s) { zs[s] = fma2(bc2(2.f), d[s], zs[s]); zt[s] = fma2(bc2(hh2), d[s], z[s]); }
            deriv(zt, d);                                       // k3
            #pragma unroll
            for (int s = 0; s < 3; ++s) { zs[s] = fma2(bc2(2.f), d[s], zs[s]); zt[s] = fma2(bc2(hh), d[s], z[s]); }
            deriv(zt, d);                                       // k4
            #pragma unroll
            for (int s = 0; s < 3; ++s) z[s] = fma2(bc2(hh6), zs[s] + d[s], z[s]);
        }
        float eh = addc;
        #pragma unroll
        for (int k = 0; k < NK; ++k) {
            float xx = z[k].x;
            amp[k] = fmaf(xx, xx, amp[k]);
            eh = fmaf(xx, dw[k], eh);
        }
        if (sub == 0) out_eh[(size_t)b * NT + t] = eh;
        if (sub < 3) {
            float2 st = {z[sub].x, z[sub].y};
            *(float2*)(out_tr + ((size_t)t * NB + b) * NS + 2 * sub) = st;
        }
    }

    if (sub < 3)
        out_amp[(size_t)b * NK + sub] = sqrtf(amp[sub] * (1.0f / NT));
}

extern "C" void kernel_launch(void* const* d_in, const int* in_sizes, int n_in,
                              void* d_out, int out_size, void* d_ws, size_t ws_size,
                              hipStream_t stream) {
    pinod_kernel<<<(NB * 8) / 256, 256, 0, stream>>>(
        (const float*)d_in[0],  (const float*)d_in[1],  (const float*)d_in[2],
        (const float*)d_in[3],  (const float*)d_in[4],  (const float*)d_in[5],
        (const float*)d_in[6],  (const float*)d_in[7],  (const float*)d_in[8],
        (const float*)d_in[9],  (const float*)d_in[10], (const float*)d_in[11],
        (const float*)d_in[12], (const float*)d_in[13], (const float*)d_in[14],
        (const float*)d_in[15], (const float*)d_in[16], (const float*)d_in[17],
        (const float*)d_in[18], (float*)d_out);
}

// Round 4
// 350.033 us; speedup vs baseline: 1.6947x; 1.6947x over previous
//
#include <hip/hip_runtime.h>
#include <math.h>

#define NB 32768
#define NT 48
#define NH 32
#define NOH 16
#define NK 3
#define NS 6
#define NSUB 4

// partner-lane value via DPP quad_perm [1,0,3,2] (xor lane^1) — VALU pipe, no LDS
__device__ __forceinline__ float dpp_xor1(float v) {
    int x = __builtin_amdgcn_update_dpp(0, __float_as_int(v), 0xB1, 0xF, 0xF, false);
    return __int_as_float(x);
}
__device__ __forceinline__ float qsum2(float v) { return v + dpp_xor1(v); }

// tanh(x) = 1 - 2/(exp(2x)+1): robust for all x
__device__ __forceinline__ float fast_tanh(float x) {
    float e = __builtin_amdgcn_exp2f(2.88539008177792681472f * x);
    return 1.0f - 2.0f * __builtin_amdgcn_rcpf(e + 1.0f);
}
__device__ __forceinline__ float gelu_exact(float x) {
    return 0.5f * x * (1.0f + erff(x * 0.70710678118654752440f));
}

__global__ void __launch_bounds__(256, 1) pinod_kernel(
    const float* __restrict__ expr,
    const float* __restrict__ t_eval,
    const float* __restrict__ enc_w1,
    const float* __restrict__ enc_b1,
    const float* __restrict__ ln_g,
    const float* __restrict__ ln_b,
    const float* __restrict__ enc_w2,
    const float* __restrict__ enc_b2,
    const float* __restrict__ enc_w3,
    const float* __restrict__ enc_b3,
    const float* __restrict__ periods,
    const float* __restrict__ gammav,
    const float* __restrict__ ode_w1,
    const float* __restrict__ ode_b1,
    const float* __restrict__ ode_w2,
    const float* __restrict__ ode_b2,
    const float* __restrict__ dec_w,
    const float* __restrict__ dec_b,
    const float* __restrict__ baseline,
    float* __restrict__ out)
{
    const int tid    = blockIdx.x * 256 + threadIdx.x;
    const int sub    = tid & 1;          // which half of the hidden units
    const int b      = tid >> 1;         // element id (lane pair {2i,2i+1})
    const int base16 = sub * 16;         // encoder h-unit slice
    const int obase  = sub * 8;          // ODE hidden-unit slice

    float* out_eh  = out;                                          // [NB][NT]
    float* out_tr  = out + (size_t)NB * NT;                        // [NT][NB][NS]
    float* out_amp = out + (size_t)NB * NT + (size_t)NT * NB * NS; // [NB][NK]

    // ================= encoder (2-way split: 16 h-units per lane) ============
    float h1r[16];
    #pragma unroll
    for (int q = 0; q < 4; ++q) {
        float4 bv = *(const float4*)(enc_b1 + base16 + 4 * q);
        h1r[4 * q] = bv.x; h1r[4 * q + 1] = bv.y; h1r[4 * q + 2] = bv.z; h1r[4 * q + 3] = bv.w;
    }
    const float4* xp = (const float4*)(expr + (size_t)b * NT);
    #pragma unroll 1
    for (int t4 = 0; t4 < NT / 4; ++t4) {
        float4 xq = xp[t4];
        float xs[4] = {xq.x, xq.y, xq.z, xq.w};
        #pragma unroll
        for (int u4 = 0; u4 < 4; ++u4) {
            const float* wr = enc_w1 + (t4 * 4 + u4) * NH + base16;
            float x = xs[u4];
            #pragma unroll
            for (int q = 0; q < 4; ++q) {
                float4 w = *(const float4*)(wr + 4 * q);
                h1r[4 * q]     = fmaf(x, w.x, h1r[4 * q]);
                h1r[4 * q + 1] = fmaf(x, w.y, h1r[4 * q + 1]);
                h1r[4 * q + 2] = fmaf(x, w.z, h1r[4 * q + 2]);
                h1r[4 * q + 3] = fmaf(x, w.w, h1r[4 * q + 3]);
            }
        }
    }
    // layernorm across all 32 (1-stage cross-lane) + gelu
    {
        float s = 0.f;
        #pragma unroll
        for (int u = 0; u < 16; ++u) s += h1r[u];
        float mu = qsum2(s) * (1.0f / NH);
        float v = 0.f;
        #pragma unroll
        for (int u = 0; u < 16; ++u) { float d = h1r[u] - mu; v = fmaf(d, d, v); }
        float var = qsum2(v) * (1.0f / NH);
        float rstd = rsqrtf(var + 1e-5f);
        #pragma unroll
        for (int q = 0; q < 4; ++q) {
            float4 g = *(const float4*)(ln_g + base16 + 4 * q);
            float4 l = *(const float4*)(ln_b + base16 + 4 * q);
            h1r[4 * q]     = gelu_exact((h1r[4 * q]     - mu) * rstd * g.x + l.x);
            h1r[4 * q + 1] = gelu_exact((h1r[4 * q + 1] - mu) * rstd * g.y + l.y);
            h1r[4 * q + 2] = gelu_exact((h1r[4 * q + 2] - mu) * rstd * g.z + l.z);
            h1r[4 * q + 3] = gelu_exact((h1r[4 * q + 3] - mu) * rstd * g.w + l.w);
        }
    }
    // h2 = gelu(h1 @ w2 + b2): lane owns j2 in [base16, base16+16)
    float acc[16];
    #pragma unroll
    for (int q = 0; q < 4; ++q) {
        float4 bv = *(const float4*)(enc_b2 + base16 + 4 * q);
        acc[4 * q] = bv.x; acc[4 * q + 1] = bv.y; acc[4 * q + 2] = bv.z; acc[4 * q + 3] = bv.w;
    }
    #pragma unroll 1
    for (int u = 0; u < 16; ++u) {
        float mine  = h1r[u];                 // value of unit base16+u
        float other = dpp_xor1(mine);         // partner's unit (16-base16)+u
        const float* wa = enc_w2 + (base16 + u) * NH + base16;
        const float* wb = enc_w2 + ((16 - base16) + u) * NH + base16;
        #pragma unroll
        for (int q = 0; q < 4; ++q) {
            float4 w1v = *(const float4*)(wa + 4 * q);
            float4 w2v = *(const float4*)(wb + 4 * q);
            acc[4 * q]     = fmaf(mine, w1v.x, fmaf(other, w2v.x, acc[4 * q]));
            acc[4 * q + 1] = fmaf(mine, w1v.y, fmaf(other, w2v.y, acc[4 * q + 1]));
            acc[4 * q + 2] = fmaf(mine, w1v.z, fmaf(other, w2v.z, acc[4 * q + 2]));
            acc[4 * q + 3] = fmaf(mine, w1v.w, fmaf(other, w2v.w, acc[4 * q + 3]));
        }
    }
    // z0 = gelu(acc) @ w3 + b3, 1-stage reduce -> replicated in both lanes
    float z[NS];
    {
        float zp[NS] = {0.f, 0.f, 0.f, 0.f, 0.f, 0.f};
        #pragma unroll 1
        for (int u = 0; u < 16; ++u) {
            float gm = gelu_exact(acc[u]);
            const float2* wp = (const float2*)(enc_w3 + (base16 + u) * NS);
            float2 w0 = wp[0], w1 = wp[1], w2 = wp[2];
            zp[0] = fmaf(gm, w0.x, zp[0]); zp[1] = fmaf(gm, w0.y, zp[1]);
            zp[2] = fmaf(gm, w1.x, zp[2]); zp[3] = fmaf(gm, w1.y, zp[3]);
            zp[4] = fmaf(gm, w2.x, zp[4]); zp[5] = fmaf(gm, w2.y, zp[5]);
        }
        #pragma unroll
        for (int s = 0; s < NS; ++s) z[s] = qsum2(zp[s]) + enc_b3[s];
    }

    // ======== ODE weights: lane owns 8 hidden units (VGPR-resident) ==========
    float w1r[NS][8];                  // w1r[i][j] = ode_w1[i][obase+j]
    #pragma unroll
    for (int i = 0; i < NS; ++i) {
        float4 wA = *(const float4*)(ode_w1 + i * NOH + obase);
        float4 wB = *(const float4*)(ode_w1 + i * NOH + obase + 4);
        w1r[i][0] = wA.x; w1r[i][1] = wA.y; w1r[i][2] = wA.z; w1r[i][3] = wA.w;
        w1r[i][4] = wB.x; w1r[i][5] = wB.y; w1r[i][6] = wB.z; w1r[i][7] = wB.w;
    }
    float b1r[8];
    {
        float4 wA = *(const float4*)(ode_b1 + obase);
        float4 wB = *(const float4*)(ode_b1 + obase + 4);
        b1r[0] = wA.x; b1r[1] = wA.y; b1r[2] = wA.z; b1r[3] = wA.w;
        b1r[4] = wB.x; b1r[5] = wB.y; b1r[6] = wB.z; b1r[7] = wB.w;
    }
    float w2r[8][NS];
    #pragma unroll
    for (int j = 0; j < 8; ++j) {
        const float2* wp = (const float2*)(ode_w2 + (obase + j) * NS);
        float2 w0 = wp[0], w1 = wp[1], w2 = wp[2];
        w2r[j][0] = w0.x; w2r[j][1] = w0.y; w2r[j][2] = w1.x;
        w2r[j][3] = w1.y; w2r[j][4] = w2.x; w2r[j][5] = w2.y;
    }

    // uniform scalars
    float om2[NK], tg[NK], dw[NK], b2u[NS];
    #pragma unroll
    for (int k = 0; k < NK; ++k) {
        float w = 6.28318530717958647693f / periods[k];
        om2[k] = w * w;
        tg[k]  = 2.0f * gammav[k];
        dw[k]  = dec_w[k];
    }
    #pragma unroll
    for (int i = 0; i < NS; ++i) b2u[i] = ode_b2[i];
    const float addc = dec_b[0] + baseline[0];

    auto deriv = [&](const float (&zz)[NS], float (&d)[NS]) {
        float a[8];
        #pragma unroll
        for (int j = 0; j < 8; ++j) a[j] = b1r[j];
        #pragma unroll
        for (int i = 0; i < NS; ++i) {
            #pragma unroll
            for (int j = 0; j < 8; ++j) a[j] = fmaf(zz[i], w1r[i][j], a[j]);
        }
        float y[8];
        #pragma unroll
        for (int j = 0; j < 8; ++j) y[j] = fast_tanh(a[j]);
        float pd[NS] = {0.f, 0.f, 0.f, 0.f, 0.f, 0.f};
        #pragma unroll
        for (int j = 0; j < 8; ++j) {
            #pragma unroll
            for (int i = 0; i < NS; ++i) pd[i] = fmaf(y[j], w2r[j][i], pd[i]);
        }
        #pragma unroll
        for (int i = 0; i < NS; ++i) pd[i] = qsum2(pd[i]);
        #pragma unroll
        for (int k = 0; k < NK; ++k) {
            float xx = zz[2 * k], vv = zz[2 * k + 1];
            d[2 * k]     = vv + pd[2 * k] + b2u[2 * k];
            d[2 * k + 1] = fmaf(-om2[k], xx, -tg[k] * vv) + pd[2 * k + 1] + b2u[2 * k + 1];
        }
    };

    // ================= t = 0 outputs =================
    float amp[NK];
    {
        float eh = addc;
        #pragma unroll
        for (int k = 0; k < NK; ++k) {
            float xx = z[2 * k];
            amp[k] = xx * xx;
            eh = fmaf(xx, dw[k], eh);
        }
        float* tp = out_tr + (size_t)b * NS;
        if (sub == 0) {
            out_eh[(size_t)b * NT] = eh;
            float2 s0 = {z[0], z[1]}, s1 = {z[2], z[3]};
            *(float2*)tp = s0; *(float2*)(tp + 2) = s1;
        } else {
            float2 s2 = {z[4], z[5]};
            *(float2*)(tp + 4) = s2;
        }
    }

    // ================= integrate =================
    float te_prev = t_eval[0];
    #pragma unroll 1
    for (int t = 1; t < NT; ++t) {
        const float te  = t_eval[t];
        const float dt  = te - te_prev;
        te_prev = te;
        const float hh  = dt * (1.0f / NSUB);
        const float hh2 = 0.5f * hh;
        const float hh6 = hh * (1.0f / 6.0f);
        #pragma unroll 1
        for (int ss = 0; ss < NSUB; ++ss) {
            float d[NS], zt[NS], zs[NS];
            deriv(z, d);                                        // k1
            #pragma unroll
            for (int i = 0; i < NS; ++i) { zs[i] = d[i]; zt[i] = fmaf(hh2, d[i], z[i]); }
            deriv(zt, d);                                       // k2
            #pragma unroll
            for (int i = 0; i < NS; ++i) { zs[i] = fmaf(2.f, d[i], zs[i]); zt[i] = fmaf(hh2, d[i], z[i]); }
            deriv(zt, d);                                       // k3
            #pragma unroll
            for (int i = 0; i < NS; ++i) { zs[i] = fmaf(2.f, d[i], zs[i]); zt[i] = fmaf(hh, d[i], z[i]); }
            deriv(zt, d);                                       // k4
            #pragma unroll
            for (int i = 0; i < NS; ++i) z[i] = fmaf(hh6, zs[i] + d[i], z[i]);
        }
        float eh = addc;
        #pragma unroll
        for (int k = 0; k < NK; ++k) {
            float xx = z[2 * k];
            amp[k] = fmaf(xx, xx, amp[k]);
            eh = fmaf(xx, dw[k], eh);
        }
        float* tp = out_tr + ((size_t)t * NB + b) * NS;
        if (sub == 0) {
            out_eh[(size_t)b * NT + t] = eh;
            float2 s0 = {z[0], z[1]}, s1 = {z[2], z[3]};
            *(float2*)tp = s0; *(float2*)(tp + 2) = s1;
        } else {
            float2 s2 = {z[4], z[5]};
            *(float2*)(tp + 4) = s2;
        }
    }

    if (sub == 0) {
        out_amp[(size_t)b * NK]     = sqrtf(amp[0] * (1.0f / NT));
        out_amp[(size_t)b * NK + 1] = sqrtf(amp[1] * (1.0f / NT));
    } else {
        out_amp[(size_t)b * NK + 2] = sqrtf(amp[2] * (1.0f / NT));
    }
}

extern "C" void kernel_launch(void* const* d_in, const int* in_sizes, int n_in,
                              void* d_out, int out_size, void* d_ws, size_t ws_size,
                              hipStream_t stream) {
    pinod_kernel<<<(NB * 2) / 256, 256, 0, stream>>>(
        (const float*)d_in[0],  (const float*)d_in[1],  (const float*)d_in[2],
        (const float*)d_in[3],  (const float*)d_in[4],  (const float*)d_in[5],
        (const float*)d_in[6],  (const float*)d_in[7],  (const float*)d_in[8],
        (const float*)d_in[9],  (const float*)d_in[10], (const float*)d_in[11],
        (const float*)d_in[12], (const float*)d_in[13], (const float*)d_in[14],
        (const float*)d_in[15], (const float*)d_in[16], (const float*)d_in[17],
        (const float*)d_in[18], (float*)d_out);
}

// Round 6
// 337.938 us; speedup vs baseline: 1.7554x; 1.0358x over previous
//
#include <hip/hip_runtime.h>
#include <math.h>

#define NB 32768
#define NT 48
#define NH 32
#define NOH 16
#define NK 3
#define NS 6
#define NSUB 4

// Force a value to stay live in a VGPR (compiler cannot rematerialize/reload)
#define PIN_V(x) asm volatile("" : "+v"(x))
// Make a wave-uniform float SGPR-resident (legal VGPR->SGPR via readfirstlane)
__device__ __forceinline__ float uni(float x) {
    return __int_as_float(__builtin_amdgcn_readfirstlane(__float_as_int(x)));
}

// partner-lane value via DPP quad_perm [1,0,3,2] (xor lane^1) — VALU pipe, no LDS
__device__ __forceinline__ float dpp_xor1(float v) {
    int x = __builtin_amdgcn_update_dpp(0, __float_as_int(v), 0xB1, 0xF, 0xF, false);
    return __int_as_float(x);
}
__device__ __forceinline__ float qsum2(float v) { return v + dpp_xor1(v); }

// tanh(x) = 1 - 2/(exp(2x)+1): robust for all x
__device__ __forceinline__ float fast_tanh(float x) {
    float e = __builtin_amdgcn_exp2f(2.88539008177792681472f * x);
    return 1.0f - 2.0f * __builtin_amdgcn_rcpf(e + 1.0f);
}
__device__ __forceinline__ float gelu_exact(float x) {
    return 0.5f * x * (1.0f + erff(x * 0.70710678118654752440f));
}

__global__ void __launch_bounds__(256, 1) pinod_kernel(
    const float* __restrict__ expr,
    const float* __restrict__ t_eval,
    const float* __restrict__ enc_w1,
    const float* __restrict__ enc_b1,
    const float* __restrict__ ln_g,
    const float* __restrict__ ln_b,
    const float* __restrict__ enc_w2,
    const float* __restrict__ enc_b2,
    const float* __restrict__ enc_w3,
    const float* __restrict__ enc_b3,
    const float* __restrict__ periods,
    const float* __restrict__ gammav,
    const float* __restrict__ ode_w1,
    const float* __restrict__ ode_b1,
    const float* __restrict__ ode_w2,
    const float* __restrict__ ode_b2,
    const float* __restrict__ dec_w,
    const float* __restrict__ dec_b,
    const float* __restrict__ baseline,
    float* __restrict__ out)
{
    const int tid    = blockIdx.x * 256 + threadIdx.x;
    const int sub    = tid & 1;          // which half of the hidden units
    const int b      = tid >> 1;         // element id (lane pair {2i,2i+1})
    const int base16 = sub * 16;         // encoder h-unit slice
    const int obase  = sub * 8;          // ODE hidden-unit slice

    float* out_eh  = out;                                          // [NB][NT]
    float* out_tr  = out + (size_t)NB * NT;                        // [NT][NB][NS]
    float* out_amp = out + (size_t)NB * NT + (size_t)NT * NB * NS; // [NB][NK]

    // ======== ODE weights: lane owns 8 hidden units — loaded FIRST and ======
    // ======== pinned into VGPRs so the hot loop never touches memory   ======
    float w1r[NS][8];                  // w1r[i][j] = ode_w1[i][obase+j]
    #pragma unroll
    for (int i = 0; i < NS; ++i) {
        float4 wA = *(const float4*)(ode_w1 + i * NOH + obase);
        float4 wB = *(const float4*)(ode_w1 + i * NOH + obase + 4);
        w1r[i][0] = wA.x; w1r[i][1] = wA.y; w1r[i][2] = wA.z; w1r[i][3] = wA.w;
        w1r[i][4] = wB.x; w1r[i][5] = wB.y; w1r[i][6] = wB.z; w1r[i][7] = wB.w;
    }
    float b1r[8];
    {
        float4 wA = *(const float4*)(ode_b1 + obase);
        float4 wB = *(const float4*)(ode_b1 + obase + 4);
        b1r[0] = wA.x; b1r[1] = wA.y; b1r[2] = wA.z; b1r[3] = wA.w;
        b1r[4] = wB.x; b1r[5] = wB.y; b1r[6] = wB.z; b1r[7] = wB.w;
    }
    float w2r[8][NS];
    #pragma unroll
    for (int j = 0; j < 8; ++j) {
        const float2* wp = (const float2*)(ode_w2 + (obase + j) * NS);
        float2 w0 = wp[0], w1 = wp[1], w2 = wp[2];
        w2r[j][0] = w0.x; w2r[j][1] = w0.y; w2r[j][2] = w1.x;
        w2r[j][3] = w1.y; w2r[j][4] = w2.x; w2r[j][5] = w2.y;
    }
    // half of ode_b2 folded into each lane's pd-accumulator init
    float hb2[NS];
    #pragma unroll
    for (int i = 0; i < NS; ++i) hb2[i] = 0.5f * ode_b2[i];

    #pragma unroll
    for (int i = 0; i < NS; ++i)
        #pragma unroll
        for (int j = 0; j < 8; ++j) PIN_V(w1r[i][j]);
    #pragma unroll
    for (int j = 0; j < 8; ++j) PIN_V(b1r[j]);
    #pragma unroll
    for (int j = 0; j < 8; ++j)
        #pragma unroll
        for (int i = 0; i < NS; ++i) PIN_V(w2r[j][i]);
    #pragma unroll
    for (int i = 0; i < NS; ++i) PIN_V(hb2[i]);

    // uniform scalars -> SGPR-resident via readfirstlane
    float nom2[NK], ntg[NK], dw[NK];
    #pragma unroll
    for (int k = 0; k < NK; ++k) {
        float w = 6.28318530717958647693f / uni(periods[k]);
        nom2[k] = uni(-(w * w));
        ntg[k]  = uni(-2.0f * gammav[k]);
        dw[k]   = uni(dec_w[k]);
    }
    const float addc = uni(dec_b[0] + baseline[0]);

    // ================= encoder (2-way split: 16 h-units per lane) ============
    float h1r[16];
    #pragma unroll
    for (int q = 0; q < 4; ++q) {
        float4 bv = *(const float4*)(enc_b1 + base16 + 4 * q);
        h1r[4 * q] = bv.x; h1r[4 * q + 1] = bv.y; h1r[4 * q + 2] = bv.z; h1r[4 * q + 3] = bv.w;
    }
    const float4* xp = (const float4*)(expr + (size_t)b * NT);
    #pragma unroll 1
    for (int t4 = 0; t4 < NT / 4; ++t4) {
        float4 xq = xp[t4];
        float xs[4] = {xq.x, xq.y, xq.z, xq.w};
        #pragma unroll
        for (int u4 = 0; u4 < 4; ++u4) {
            const float* wr = enc_w1 + (t4 * 4 + u4) * NH + base16;
            float x = xs[u4];
            #pragma unroll
            for (int q = 0; q < 4; ++q) {
                float4 w = *(const float4*)(wr + 4 * q);
                h1r[4 * q]     = fmaf(x, w.x, h1r[4 * q]);
                h1r[4 * q + 1] = fmaf(x, w.y, h1r[4 * q + 1]);
                h1r[4 * q + 2] = fmaf(x, w.z, h1r[4 * q + 2]);
                h1r[4 * q + 3] = fmaf(x, w.w, h1r[4 * q + 3]);
            }
        }
    }
    // layernorm across all 32 (1-stage cross-lane) + gelu
    {
        float s = 0.f;
        #pragma unroll
        for (int u = 0; u < 16; ++u) s += h1r[u];
        float mu = qsum2(s) * (1.0f / NH);
        float v = 0.f;
        #pragma unroll
        for (int u = 0; u < 16; ++u) { float d = h1r[u] - mu; v = fmaf(d, d, v); }
        float var = qsum2(v) * (1.0f / NH);
        float rstd = rsqrtf(var + 1e-5f);
        #pragma unroll
        for (int q = 0; q < 4; ++q) {
            float4 g = *(const float4*)(ln_g + base16 + 4 * q);
            float4 l = *(const float4*)(ln_b + base16 + 4 * q);
            h1r[4 * q]     = gelu_exact((h1r[4 * q]     - mu) * rstd * g.x + l.x);
            h1r[4 * q + 1] = gelu_exact((h1r[4 * q + 1] - mu) * rstd * g.y + l.y);
            h1r[4 * q + 2] = gelu_exact((h1r[4 * q + 2] - mu) * rstd * g.z + l.z);
            h1r[4 * q + 3] = gelu_exact((h1r[4 * q + 3] - mu) * rstd * g.w + l.w);
        }
    }
    // h2 = gelu(h1 @ w2 + b2): lane owns j2 in [base16, base16+16)
    float acc[16];
    #pragma unroll
    for (int q = 0; q < 4; ++q) {
        float4 bv = *(const float4*)(enc_b2 + base16 + 4 * q);
        acc[4 * q] = bv.x; acc[4 * q + 1] = bv.y; acc[4 * q + 2] = bv.z; acc[4 * q + 3] = bv.w;
    }
    #pragma unroll 1
    for (int u = 0; u < 16; ++u) {
        float mine  = h1r[u];                 // value of unit base16+u
        float other = dpp_xor1(mine);         // partner's unit (16-base16)+u
        const float* wa = enc_w2 + (base16 + u) * NH + base16;
        const float* wb = enc_w2 + ((16 - base16) + u) * NH + base16;
        #pragma unroll
        for (int q = 0; q < 4; ++q) {
            float4 w1v = *(const float4*)(wa + 4 * q);
            float4 w2v = *(const float4*)(wb + 4 * q);
            acc[4 * q]     = fmaf(mine, w1v.x, fmaf(other, w2v.x, acc[4 * q]));
            acc[4 * q + 1] = fmaf(mine, w1v.y, fmaf(other, w2v.y, acc[4 * q + 1]));
            acc[4 * q + 2] = fmaf(mine, w1v.z, fmaf(other, w2v.z, acc[4 * q + 2]));
            acc[4 * q + 3] = fmaf(mine, w1v.w, fmaf(other, w2v.w, acc[4 * q + 3]));
        }
    }
    // z0 = gelu(acc) @ w3 + b3, 1-stage reduce -> replicated in both lanes
    float z[NS];
    {
        float zp[NS] = {0.f, 0.f, 0.f, 0.f, 0.f, 0.f};
        #pragma unroll 1
        for (int u = 0; u < 16; ++u) {
            float gm = gelu_exact(acc[u]);
            const float2* wp = (const float2*)(enc_w3 + (base16 + u) * NS);
            float2 w0 = wp[0], w1 = wp[1], w2 = wp[2];
            zp[0] = fmaf(gm, w0.x, zp[0]); zp[1] = fmaf(gm, w0.y, zp[1]);
            zp[2] = fmaf(gm, w1.x, zp[2]); zp[3] = fmaf(gm, w1.y, zp[3]);
            zp[4] = fmaf(gm, w2.x, zp[4]); zp[5] = fmaf(gm, w2.y, zp[5]);
        }
        #pragma unroll
        for (int s = 0; s < NS; ++s) z[s] = qsum2(zp[s]) + enc_b3[s];
    }

    auto deriv = [&](const float (&zz)[NS], float (&d)[NS]) {
        float a[8];
        #pragma unroll
        for (int j = 0; j < 8; ++j) a[j] = b1r[j];
        #pragma unroll
        for (int i = 0; i < NS; ++i) {
            #pragma unroll
            for (int j = 0; j < 8; ++j) a[j] = fmaf(zz[i], w1r[i][j], a[j]);
        }
        float y[8];
        #pragma unroll
        for (int j = 0; j < 8; ++j) y[j] = fast_tanh(a[j]);
        float pd[NS];
        #pragma unroll
        for (int i = 0; i < NS; ++i) pd[i] = hb2[i];   // b2 folded (x2 via reduce)
        #pragma unroll
        for (int j = 0; j < 8; ++j) {
            #pragma unroll
            for (int i = 0; i < NS; ++i) pd[i] = fmaf(y[j], w2r[j][i], pd[i]);
        }
        #pragma unroll
        for (int i = 0; i < NS; ++i) pd[i] = qsum2(pd[i]);
        #pragma unroll
        for (int k = 0; k < NK; ++k) {
            float xx = zz[2 * k], vv = zz[2 * k + 1];
            d[2 * k]     = vv + pd[2 * k];
            d[2 * k + 1] = fmaf(nom2[k], xx, ntg[k] * vv) + pd[2 * k + 1];
        }
    };

    // ================= t = 0 outputs =================
    float amp[NK];
    {
        float eh = addc;
        #pragma unroll
        for (int k = 0; k < NK; ++k) {
            float xx = z[2 * k];
            amp[k] = xx * xx;
            eh = fmaf(xx, dw[k], eh);
        }
        float* tp = out_tr + (size_t)b * NS;
        if (sub == 0) {
            out_eh[(size_t)b * NT] = eh;
            float2 s0 = {z[0], z[1]}, s1 = {z[2], z[3]};
            *(float2*)tp = s0; *(float2*)(tp + 2) = s1;
        } else {
            float2 s2 = {z[4], z[5]};
            *(float2*)(tp + 4) = s2;
        }
    }

    // ================= integrate =================
    float te_prev = t_eval[0];
    #pragma unroll 1
    for (int t = 1; t < NT; ++t) {
        const float te  = t_eval[t];
        const float dt  = te - te_prev;
        te_prev = te;
        const float hh  = dt * (1.0f / NSUB);
        const float hh2 = 0.5f * hh;
        const float hh6 = hh * (1.0f / 6.0f);
        #pragma unroll 1
        for (int ss = 0; ss < NSUB; ++ss) {
            float d[NS], zt[NS], zs[NS];
            deriv(z, d);                                        // k1
            #pragma unroll
            for (int i = 0; i < NS; ++i) { zs[i] = d[i]; zt[i] = fmaf(hh2, d[i], z[i]); }
            deriv(zt, d);                                       // k2
            #pragma unroll
            for (int i = 0; i < NS; ++i) { zs[i] = fmaf(2.f, d[i], zs[i]); zt[i] = fmaf(hh2, d[i], z[i]); }
            deriv(zt, d);                                       // k3
            #pragma unroll
            for (int i = 0; i < NS; ++i) { zs[i] = fmaf(2.f, d[i], zs[i]); zt[i] = fmaf(hh, d[i], z[i]); }
            deriv(zt, d);                                       // k4
            #pragma unroll
            for (int i = 0; i < NS; ++i) z[i] = fmaf(hh6, zs[i] + d[i], z[i]);
        }
        float eh = addc;
        #pragma unroll
        for (int k = 0; k < NK; ++k) {
            float xx = z[2 * k];
            amp[k] = fmaf(xx, xx, amp[k]);
            eh = fmaf(xx, dw[k], eh);
        }
        float* tp = out_tr + ((size_t)t * NB + b) * NS;
        if (sub == 0) {
            out_eh[(size_t)b * NT + t] = eh;
            float2 s0 = {z[0], z[1]}, s1 = {z[2], z[3]};
            *(float2*)tp = s0; *(float2*)(tp + 2) = s1;
        } else {
            float2 s2 = {z[4], z[5]};
            *(float2*)(tp + 4) = s2;
        }
    }

    if (sub == 0) {
        out_amp[(size_t)b * NK]     = sqrtf(amp[0] * (1.0f / NT));
        out_amp[(size_t)b * NK + 1] = sqrtf(amp[1] * (1.0f / NT));
    } else {
        out_amp[(size_t)b * NK + 2] = sqrtf(amp[2] * (1.0f / NT));
    }
}

extern "C" void kernel_launch(void* const* d_in, const int* in_sizes, int n_in,
                              void* d_out, int out_size, void* d_ws, size_t ws_size,
                              hipStream_t stream) {
    pinod_kernel<<<(NB * 2) / 256, 256, 0, stream>>>(
        (const float*)d_in[0],  (const float*)d_in[1],  (const float*)d_in[2],
        (const float*)d_in[3],  (const float*)d_in[4],  (const float*)d_in[5],
        (const float*)d_in[6],  (const float*)d_in[7],  (const float*)d_in[8],
        (const float*)d_in[9],  (const float*)d_in[10], (const float*)d_in[11],
        (const float*)d_in[12], (const float*)d_in[13], (const float*)d_in[14],
        (const float*)d_in[15], (const float*)d_in[16], (const float*)d_in[17],
        (const float*)d_in[18], (float*)d_out);
}